// Round 2
// baseline (955.633 us; speedup 1.0000x reference)
//
#include <hip/hip_runtime.h>
#include <stdint.h>

// Problem constants
#define ZSIZE   8388608      // 32*256*32*32
#define NPIX    32768        // 32*32*32
#define IDX_OFF ZSIZE        // idx output offset (floats) in d_out
#define LOSS_OFF (ZSIZE + NPIX)
#define ET_OFF  1024         // Et scratch offset (words) in d_out[0..ZSIZE) region
                             // d_out[0..1024) = se scratch; both overwritten by kout later.

// async global->LDS, 16B per lane. Requires: per-wave, LDS dests are
// base + lane*16 contiguous in lane order (true for all uses below).
typedef const __attribute__((address_space(1))) void gv_t;
typedef __attribute__((address_space(3))) void sv_t;
__device__ __forceinline__ void gl_lds16(const float* g, float* l) {
  __builtin_amdgcn_global_load_lds((gv_t*)g, (sv_t*)l, 16, 0, 0);
}

// ---------------------------------------------------------------------------
// ktr: transpose embedding E[1024][256] -> Et[256][1024] in d_out scratch
// ---------------------------------------------------------------------------
__global__ __launch_bounds__(256) void ktr(const float* __restrict__ E,
                                           float* __restrict__ out) {
  __shared__ float tile[64][65];
  const int k0 = blockIdx.x * 64;
  const int c0 = blockIdx.y * 64;
  const int t = threadIdx.x;
  #pragma unroll
  for (int i = 0; i < 4; i++) {
    int f = t + 256 * i;
    int r = f >> 4, q = f & 15;
    float4 e = *(const float4*)(E + (k0 + r) * 256 + c0 + 4 * q);
    tile[r][4 * q + 0] = e.x; tile[r][4 * q + 1] = e.y;
    tile[r][4 * q + 2] = e.z; tile[r][4 * q + 3] = e.w;
  }
  __syncthreads();
  #pragma unroll
  for (int i = 0; i < 4; i++) {
    int f = t + 256 * i;
    int cr = f >> 4, kq = f & 15;
    float4 o;
    o.x = tile[4 * kq + 0][cr];
    o.y = tile[4 * kq + 1][cr];
    o.z = tile[4 * kq + 2][cr];
    o.w = tile[4 * kq + 3][cr];
    *(float4*)(out + ET_OFF + (c0 + cr) * 1024 + k0 + 4 * kq) = o;
  }
}

// ---------------------------------------------------------------------------
// kse: se[k] = ascending-c sequential sum of E[k][c]^2 (order must match R1
// exactly — idx bit-faithfulness). Coalesced via Et.
// ---------------------------------------------------------------------------
__global__ __launch_bounds__(256) void kse(float* __restrict__ out) {
  const int k = blockIdx.x * 256 + threadIdx.x;
  const float* Et = out + ET_OFF;
  float acc = 0.0f;
  #pragma unroll 8
  for (int c = 0; c < 256; c++) {
    float v = Et[c * 1024 + k];
    acc = __fadd_rn(acc, __fmul_rn(v, v));
  }
  out[k] = acc;
}

// ---------------------------------------------------------------------------
// kmain: fused distance GEMM + argmin.
// Block = (ccg,b): 16 channel-rows x 4 w-offsets = 64 pixels, all 1024 codes.
// Thread grid: pg = t>>5 (8 pixel-groups of 8 pixels: rows 2pg,2pg+1 x w0 0..3),
//              cg = t&31 (16 codes per kt-tile of 512).
// Micro-tile 8x16, acc in 128 VGPRs. Vs (64KB) resident; Es[8][512] (16KB)
// staged per 8-c chunk via global_load_lds. LDS = exactly 80KB -> 2 blocks/CU.
// dist = fl(fl(se+sz) - fl(2*dot)), dot = ascending-c fp32 FMA chain
// (bit-identical to R1). Argmin first-index; cross-cg merge via shfl_xor
// with (d, idx) lexicographic min.
// ---------------------------------------------------------------------------
__global__ __launch_bounds__(256, 2) void kmain(const float* __restrict__ z,
                                                float* __restrict__ out) {
  __shared__ __attribute__((aligned(16))) float Vs[16 * 1024];  // 64 KB
  __shared__ __attribute__((aligned(16))) float Es[8 * 512];    // 16 KB

  const int t = threadIdx.x;
  const int ccg = blockIdx.x;       // 0..15
  const int b = blockIdx.y;         // 0..31
  const int cc0 = ccg * 16;
  const int pg = t >> 5;            // 0..7
  const int cg = t & 31;            // 0..31
  const float* zb = z + (size_t)b * 262144;
  const float* se_g = out;
  const float* Et_g = out + ET_OFF;

  // ---- stage V-tile: 16 contiguous rows of 1024 floats (async) ----
  #pragma unroll
  for (int i2 = 0; i2 < 16; i2++) {
    int f = t + 256 * i2;           // 0..4095 float4s
    int r = f >> 8, q = f & 255;
    gl_lds16(zb + (cc0 + r) * 1024 + 4 * q, Vs + r * 1024 + 4 * q);
  }
  __syncthreads();

  // ---- sz per pixel: np-faithful sequential ascending-c, mul then add ----
  // (temporarily parked in Es[0..63], then pulled into registers)
  if (t < 64) {
    int r = t >> 2, w0 = t & 3;
    float a = 0.0f;
    for (int c = 0; c < 256; c++) {
      float v = Vs[r * 1024 + 4 * c + w0];
      a = __fadd_rn(a, __fmul_rn(v, v));
    }
    Es[t] = a;                      // pixel p = t = r*4 + w0
  }
  __syncthreads();
  float szr[8];
  #pragma unroll
  for (int i = 0; i < 8; i++) szr[i] = Es[8 * pg + i];  // broadcast, conflict-free

  float bestd[8];
  int besti[8];
  #pragma unroll
  for (int i = 0; i < 8; i++) { bestd[i] = 3.4e38f; besti[i] = 0; }

  for (int kt = 0; kt < 2; kt++) {
    const int k0 = kt * 512;
    float acc[8][16];
    #pragma unroll
    for (int i = 0; i < 8; i++)
      #pragma unroll
      for (int j = 0; j < 16; j++) acc[i][j] = 0.0f;

    for (int ci = 0; ci < 32; ci++) {
      const int c0 = ci * 8;
      __syncthreads();              // Es readers of previous chunk done
      #pragma unroll
      for (int i2 = 0; i2 < 4; i2++) {
        int f = t + 256 * i2;       // 0..1023 float4s
        int r = f >> 7, q = f & 127;
        gl_lds16(Et_g + (c0 + r) * 1024 + k0 + 4 * q, Es + r * 512 + 4 * q);
      }
      __syncthreads();

      #pragma unroll 2
      for (int c = 0; c < 8; c++) {
        float4 va = *(const float4*)(Vs + (2 * pg) * 1024 + 4 * (c0 + c));
        float4 vb = *(const float4*)(Vs + (2 * pg + 1) * 1024 + 4 * (c0 + c));
        float4 e0 = *(const float4*)(Es + c * 512 + 16 * cg);
        float4 e1 = *(const float4*)(Es + c * 512 + 16 * cg + 4);
        float4 e2 = *(const float4*)(Es + c * 512 + 16 * cg + 8);
        float4 e3 = *(const float4*)(Es + c * 512 + 16 * cg + 12);
        float vv[8] = {va.x, va.y, va.z, va.w, vb.x, vb.y, vb.z, vb.w};
        float ee[16] = {e0.x, e0.y, e0.z, e0.w, e1.x, e1.y, e1.z, e1.w,
                        e2.x, e2.y, e2.z, e2.w, e3.x, e3.y, e3.z, e3.w};
        #pragma unroll
        for (int i = 0; i < 8; i++)
          #pragma unroll
          for (int j = 0; j < 16; j++)
            acc[i][j] = __fmaf_rn(vv[i], ee[j], acc[i][j]);
      }
    }

    // ---- epilogue: dist + running argmin (codes strictly ascending) ----
    float se16[16];
    {
      float4 s0 = *(const float4*)(se_g + k0 + 16 * cg);
      float4 s1 = *(const float4*)(se_g + k0 + 16 * cg + 4);
      float4 s2 = *(const float4*)(se_g + k0 + 16 * cg + 8);
      float4 s3 = *(const float4*)(se_g + k0 + 16 * cg + 12);
      se16[0] = s0.x; se16[1] = s0.y; se16[2] = s0.z; se16[3] = s0.w;
      se16[4] = s1.x; se16[5] = s1.y; se16[6] = s1.z; se16[7] = s1.w;
      se16[8] = s2.x; se16[9] = s2.y; se16[10] = s2.z; se16[11] = s2.w;
      se16[12] = s3.x; se16[13] = s3.y; se16[14] = s3.z; se16[15] = s3.w;
    }
    #pragma unroll
    for (int i = 0; i < 8; i++) {
      float szv = szr[i];
      #pragma unroll
      for (int j = 0; j < 16; j++) {
        float d = __fsub_rn(__fadd_rn(se16[j], szv), __fmul_rn(2.0f, acc[i][j]));
        if (d < bestd[i]) { bestd[i] = d; besti[i] = k0 + 16 * cg + j; }
      }
    }
  }

  // ---- cross-cg argmin merge: 32-lane butterfly, (d,idx) lexicographic ----
  #pragma unroll
  for (int i = 0; i < 8; i++) {
    float bd = bestd[i]; int bi = besti[i];
    #pragma unroll
    for (int m = 16; m >= 1; m >>= 1) {
      float d2 = __shfl_xor(bd, m, 64);
      int i2 = __shfl_xor(bi, m, 64);
      if (d2 < bd || (d2 == bd && i2 < bi)) { bd = d2; bi = i2; }
    }
    if (cg == 0) {
      int r = 2 * pg + (i >> 2), w0 = i & 3;
      int n = w0 * 256 + cc0 + r;
      out[IDX_OFF + b * 1024 + n] = (float)bi;
    }
  }
}

// ---------------------------------------------------------------------------
// kout: z_q_st = fl(zp + fl(zq - zp)); per-block loss partial -> d_ws
// ---------------------------------------------------------------------------
__global__ __launch_bounds__(256) void kout(const float* __restrict__ z,
                                            const float* __restrict__ E,
                                            float* __restrict__ out,
                                            float* __restrict__ ws) {
  __shared__ float red[4];
  const int t = threadIdx.x;
  const size_t g4 = (size_t)blockIdx.x * 256 + t;
  const size_t g = g4 * 4;
  const int b = (int)(g >> 18);
  const int c = (int)((g >> 10) & 255);
  const int n = (int)(g & 1023);

  float4 zp = *(const float4*)(z + g);
  float4 idxf = *(const float4*)(out + IDX_OFF + b * 1024 + n);
  int i0 = (int)idxf.x, i1 = (int)idxf.y, i2 = (int)idxf.z, i3 = (int)idxf.w;
  float q0 = E[i0 * 256 + c];
  float q1 = E[i1 * 256 + c];
  float q2 = E[i2 * 256 + c];
  float q3 = E[i3 * 256 + c];
  float d0 = __fsub_rn(q0, zp.x);
  float d1 = __fsub_rn(q1, zp.y);
  float d2 = __fsub_rn(q2, zp.z);
  float d3 = __fsub_rn(q3, zp.w);
  float4 o;
  o.x = __fadd_rn(zp.x, d0);
  o.y = __fadd_rn(zp.y, d1);
  o.z = __fadd_rn(zp.z, d2);
  o.w = __fadd_rn(zp.w, d3);
  *(float4*)(out + g) = o;

  float s = d0 * d0 + d1 * d1 + d2 * d2 + d3 * d3;
  #pragma unroll
  for (int off = 32; off > 0; off >>= 1) s += __shfl_down(s, off);
  if ((t & 63) == 0) red[t >> 6] = s;
  __syncthreads();
  if (t == 0) ws[blockIdx.x] = red[0] + red[1] + red[2] + red[3];
}

// ---------------------------------------------------------------------------
// kfin: loss = 1.25 * (sum(ws)/N)
// ---------------------------------------------------------------------------
__global__ __launch_bounds__(256) void kfin(const float* __restrict__ ws,
                                            float* __restrict__ out) {
  __shared__ float red[4];
  const int t = threadIdx.x;
  float s = 0.0f;
  #pragma unroll
  for (int i = 0; i < 32; i++) s += ws[t + 256 * i];
  #pragma unroll
  for (int off = 32; off > 0; off >>= 1) s += __shfl_down(s, off);
  if ((t & 63) == 0) red[t >> 6] = s;
  __syncthreads();
  if (t == 0) {
    float S = red[0] + red[1] + red[2] + red[3];
    float m = S / 8388608.0f;
    out[LOSS_OFF] = __fadd_rn(m, __fmul_rn(0.25f, m));
  }
}

extern "C" void kernel_launch(void* const* d_in, const int* in_sizes, int n_in,
                              void* d_out, int out_size, void* d_ws, size_t ws_size,
                              hipStream_t stream) {
  const float* z = (const float*)d_in[0];    // [32,256,32,32]
  const float* E = (const float*)d_in[1];    // [1024,256]
  float* out = (float*)d_out;
  float* ws = (float*)d_ws;                  // 8192 floats of partials

  ktr<<<dim3(16, 4), 256, 0, stream>>>(E, out);
  kse<<<dim3(4), 256, 0, stream>>>(out);
  kmain<<<dim3(16, 32), 256, 0, stream>>>(z, out);
  kout<<<dim3(8192), 256, 0, stream>>>(z, E, out, ws);
  kfin<<<dim3(1), 256, 0, stream>>>(ws, out);
}

// Round 3
// 345.034 us; speedup vs baseline: 2.7697x; 2.7697x over previous
//
#include <hip/hip_runtime.h>
#include <stdint.h>

// Problem constants
#define ZSIZE   8388608      // 32*256*32*32
#define NPIX    32768        // 32*32*32
#define IDX_OFF ZSIZE        // idx output offset (floats) in d_out
#define LOSS_OFF (ZSIZE + NPIX)
#define ET_OFF  1024         // Et scratch offset (words) in d_out[0..ZSIZE) region
                             // d_out[0..1024) = se scratch; both overwritten by kout later.

// async global->LDS, 16B per lane. Requires: per-wave, LDS dests are
// base + lane*16 contiguous in lane order (true for all uses below).
typedef const __attribute__((address_space(1))) void gv_t;
typedef __attribute__((address_space(3))) void sv_t;
__device__ __forceinline__ void gl_lds16(const float* g, float* l) {
  __builtin_amdgcn_global_load_lds((gv_t*)g, (sv_t*)l, 16, 0, 0);
}

// ---------------------------------------------------------------------------
// ktr: transpose embedding E[1024][256] -> Et[256][1024] in d_out scratch
// ---------------------------------------------------------------------------
__global__ __launch_bounds__(256) void ktr(const float* __restrict__ E,
                                           float* __restrict__ out) {
  __shared__ float tile[64][65];
  const int k0 = blockIdx.x * 64;
  const int c0 = blockIdx.y * 64;
  const int t = threadIdx.x;
  #pragma unroll
  for (int i = 0; i < 4; i++) {
    int f = t + 256 * i;
    int r = f >> 4, q = f & 15;
    float4 e = *(const float4*)(E + (k0 + r) * 256 + c0 + 4 * q);
    tile[r][4 * q + 0] = e.x; tile[r][4 * q + 1] = e.y;
    tile[r][4 * q + 2] = e.z; tile[r][4 * q + 3] = e.w;
  }
  __syncthreads();
  #pragma unroll
  for (int i = 0; i < 4; i++) {
    int f = t + 256 * i;
    int cr = f >> 4, kq = f & 15;
    float4 o;
    o.x = tile[4 * kq + 0][cr];
    o.y = tile[4 * kq + 1][cr];
    o.z = tile[4 * kq + 2][cr];
    o.w = tile[4 * kq + 3][cr];
    *(float4*)(out + ET_OFF + (c0 + cr) * 1024 + k0 + 4 * kq) = o;
  }
}

// ---------------------------------------------------------------------------
// kse: se[k] = ascending-c sequential sum of E[k][c]^2 (order must match
// reference fp32 chain — idx bit-faithfulness). Coalesced via Et.
// ---------------------------------------------------------------------------
__global__ __launch_bounds__(256) void kse(float* __restrict__ out) {
  const int k = blockIdx.x * 256 + threadIdx.x;
  const float* Et = out + ET_OFF;
  float acc = 0.0f;
  #pragma unroll 8
  for (int c = 0; c < 256; c++) {
    float v = Et[c * 1024 + k];
    acc = __fadd_rn(acc, __fmul_rn(v, v));
  }
  out[k] = acc;
}

// ---------------------------------------------------------------------------
// kmain: fused distance GEMM + argmin.
// Block = (ccg,b): 16 channel-rows x 4 w-offsets = 64 pixels, all 1024 codes.
// Thread grid: pg = t>>5 (8 pixel-groups: rows 2pg,2pg+1 x w0 0..3),
//              cg = t&31.
// Per kt-tile of 512 codes, thread cg owns codes {4cg+128j+l : j,l in 0..3}
// -> Es float4 reads at f = cg + 32j: bank-group f%8 = cg%8, uniform over all
// 8 groups = conflict-free b128 (the R2 16-contiguous-codes mapping hit only
// 2 of 8 groups -> 16-way conflict -> 4.4e8 conflict cycles. Fixed here.)
// Micro-tile 8x16 (acc 128 VGPR). Vs (64KB) resident, reads are half-wave
// broadcasts (free). Es[8][512] (16KB) staged per 8-c chunk via
// global_load_lds. LDS = 80KB -> 2 blocks/CU.
// dist = fl(fl(se+sz) - fl(2*dot)), dot = ascending-c fp32 FMA chain.
// Argmin first-index; cross-cg merge via shfl_xor, (d,idx) lexicographic.
// ---------------------------------------------------------------------------
__global__ __launch_bounds__(256, 2) void kmain(const float* __restrict__ z,
                                                float* __restrict__ out) {
  __shared__ __attribute__((aligned(16))) float Vs[16 * 1024];  // 64 KB
  __shared__ __attribute__((aligned(16))) float Es[8 * 512];    // 16 KB

  const int t = threadIdx.x;
  const int ccg = blockIdx.x;       // 0..15
  const int b = blockIdx.y;         // 0..31
  const int cc0 = ccg * 16;
  const int pg = t >> 5;            // 0..7
  const int cg = t & 31;            // 0..31
  const float* zb = z + (size_t)b * 262144;
  const float* se_g = out;
  const float* Et_g = out + ET_OFF;

  // ---- stage V-tile: 16 contiguous rows of 1024 floats (async) ----
  #pragma unroll
  for (int i2 = 0; i2 < 16; i2++) {
    int f = t + 256 * i2;           // 0..4095 float4s
    int r = f >> 8, q = f & 255;
    gl_lds16(zb + (cc0 + r) * 1024 + 4 * q, Vs + r * 1024 + 4 * q);
  }
  __syncthreads();

  // ---- sz per pixel: np-faithful sequential ascending-c, mul then add ----
  // (parked in Es[0..63], pulled to registers before first staging chunk)
  if (t < 64) {
    int r = t >> 2, w0 = t & 3;
    float a = 0.0f;
    for (int c = 0; c < 256; c++) {
      float v = Vs[r * 1024 + 4 * c + w0];
      a = __fadd_rn(a, __fmul_rn(v, v));
    }
    Es[t] = a;                      // pixel p = t = r*4 + w0
  }
  __syncthreads();
  float szr[8];
  #pragma unroll
  for (int i = 0; i < 8; i++) szr[i] = Es[8 * pg + i];  // broadcast, conflict-free

  float bestd[8];
  int besti[8];
  #pragma unroll
  for (int i = 0; i < 8; i++) { bestd[i] = 3.4e38f; besti[i] = 0; }

  for (int kt = 0; kt < 2; kt++) {
    const int k0 = kt * 512;
    float acc[8][16];
    #pragma unroll
    for (int i = 0; i < 8; i++)
      #pragma unroll
      for (int j = 0; j < 16; j++) acc[i][j] = 0.0f;

    for (int ci = 0; ci < 32; ci++) {
      const int c0 = ci * 8;
      __syncthreads();              // Es readers of previous chunk done
      #pragma unroll
      for (int i2 = 0; i2 < 4; i2++) {
        int f = t + 256 * i2;       // 0..1023 float4s
        int r = f >> 7, q = f & 127;
        gl_lds16(Et_g + (c0 + r) * 1024 + k0 + 4 * q, Es + r * 512 + 4 * q);
      }
      __syncthreads();

      #pragma unroll 2
      for (int c = 0; c < 8; c++) {
        float4 va = *(const float4*)(Vs + (2 * pg) * 1024 + 4 * (c0 + c));
        float4 vb = *(const float4*)(Vs + (2 * pg + 1) * 1024 + 4 * (c0 + c));
        // conflict-free pattern: float4 index f = cg + 32*j  (f%8 == cg%8)
        float4 e0 = *(const float4*)(Es + c * 512 + 4 * cg);
        float4 e1 = *(const float4*)(Es + c * 512 + 4 * cg + 128);
        float4 e2 = *(const float4*)(Es + c * 512 + 4 * cg + 256);
        float4 e3 = *(const float4*)(Es + c * 512 + 4 * cg + 384);
        float vv[8] = {va.x, va.y, va.z, va.w, vb.x, vb.y, vb.z, vb.w};
        float ee[16] = {e0.x, e0.y, e0.z, e0.w, e1.x, e1.y, e1.z, e1.w,
                        e2.x, e2.y, e2.z, e2.w, e3.x, e3.y, e3.z, e3.w};
        #pragma unroll
        for (int i = 0; i < 8; i++)
          #pragma unroll
          for (int j = 0; j < 16; j++)
            acc[i][j] = __fmaf_rn(vv[i], ee[j], acc[i][j]);
      }
    }

    // ---- epilogue: dist + running argmin ----
    // acc[i][4*j+l] corresponds to code k0 + 4*cg + 128*j + l
    float se16[16];
    {
      float4 s0 = *(const float4*)(se_g + k0 + 4 * cg);
      float4 s1 = *(const float4*)(se_g + k0 + 4 * cg + 128);
      float4 s2 = *(const float4*)(se_g + k0 + 4 * cg + 256);
      float4 s3 = *(const float4*)(se_g + k0 + 4 * cg + 384);
      se16[0] = s0.x; se16[1] = s0.y; se16[2] = s0.z; se16[3] = s0.w;
      se16[4] = s1.x; se16[5] = s1.y; se16[6] = s1.z; se16[7] = s1.w;
      se16[8] = s2.x; se16[9] = s2.y; se16[10] = s2.z; se16[11] = s2.w;
      se16[12] = s3.x; se16[13] = s3.y; se16[14] = s3.z; se16[15] = s3.w;
    }
    #pragma unroll
    for (int i = 0; i < 8; i++) {
      float szv = szr[i];
      #pragma unroll
      for (int j = 0; j < 4; j++)
        #pragma unroll
        for (int l = 0; l < 4; l++) {
          float d = __fsub_rn(__fadd_rn(se16[4 * j + l], szv),
                              __fmul_rn(2.0f, acc[i][4 * j + l]));
          // ascending-code iteration + strict < == first-index argmin
          if (d < bestd[i]) { bestd[i] = d; besti[i] = k0 + 4 * cg + 128 * j + l; }
        }
    }
  }

  // ---- cross-cg argmin merge: 32-lane butterfly, (d,idx) lexicographic ----
  #pragma unroll
  for (int i = 0; i < 8; i++) {
    float bd = bestd[i]; int bi = besti[i];
    #pragma unroll
    for (int m = 16; m >= 1; m >>= 1) {
      float d2 = __shfl_xor(bd, m, 64);
      int i2 = __shfl_xor(bi, m, 64);
      if (d2 < bd || (d2 == bd && i2 < bi)) { bd = d2; bi = i2; }
    }
    if (cg == 0) {
      int r = 2 * pg + (i >> 2), w0 = i & 3;
      int n = w0 * 256 + cc0 + r;
      out[IDX_OFF + b * 1024 + n] = (float)bi;
    }
  }
}

// ---------------------------------------------------------------------------
// kout: z_q_st = fl(zp + fl(zq - zp)); per-block loss partial -> d_ws
// ---------------------------------------------------------------------------
__global__ __launch_bounds__(256) void kout(const float* __restrict__ z,
                                            const float* __restrict__ E,
                                            float* __restrict__ out,
                                            float* __restrict__ ws) {
  __shared__ float red[4];
  const int t = threadIdx.x;
  const size_t g4 = (size_t)blockIdx.x * 256 + t;
  const size_t g = g4 * 4;
  const int b = (int)(g >> 18);
  const int c = (int)((g >> 10) & 255);
  const int n = (int)(g & 1023);

  float4 zp = *(const float4*)(z + g);
  float4 idxf = *(const float4*)(out + IDX_OFF + b * 1024 + n);
  int i0 = (int)idxf.x, i1 = (int)idxf.y, i2 = (int)idxf.z, i3 = (int)idxf.w;
  float q0 = E[i0 * 256 + c];
  float q1 = E[i1 * 256 + c];
  float q2 = E[i2 * 256 + c];
  float q3 = E[i3 * 256 + c];
  float d0 = __fsub_rn(q0, zp.x);
  float d1 = __fsub_rn(q1, zp.y);
  float d2 = __fsub_rn(q2, zp.z);
  float d3 = __fsub_rn(q3, zp.w);
  float4 o;
  o.x = __fadd_rn(zp.x, d0);
  o.y = __fadd_rn(zp.y, d1);
  o.z = __fadd_rn(zp.z, d2);
  o.w = __fadd_rn(zp.w, d3);
  *(float4*)(out + g) = o;

  float s = d0 * d0 + d1 * d1 + d2 * d2 + d3 * d3;
  #pragma unroll
  for (int off = 32; off > 0; off >>= 1) s += __shfl_down(s, off);
  if ((t & 63) == 0) red[t >> 6] = s;
  __syncthreads();
  if (t == 0) ws[blockIdx.x] = red[0] + red[1] + red[2] + red[3];
}

// ---------------------------------------------------------------------------
// kfin: loss = 1.25 * (sum(ws)/N)
// ---------------------------------------------------------------------------
__global__ __launch_bounds__(256) void kfin(const float* __restrict__ ws,
                                            float* __restrict__ out) {
  __shared__ float red[4];
  const int t = threadIdx.x;
  float s = 0.0f;
  #pragma unroll
  for (int i = 0; i < 32; i++) s += ws[t + 256 * i];
  #pragma unroll
  for (int off = 32; off > 0; off >>= 1) s += __shfl_down(s, off);
  if ((t & 63) == 0) red[t >> 6] = s;
  __syncthreads();
  if (t == 0) {
    float S = red[0] + red[1] + red[2] + red[3];
    float m = S / 8388608.0f;
    out[LOSS_OFF] = __fadd_rn(m, __fmul_rn(0.25f, m));
  }
}

extern "C" void kernel_launch(void* const* d_in, const int* in_sizes, int n_in,
                              void* d_out, int out_size, void* d_ws, size_t ws_size,
                              hipStream_t stream) {
  const float* z = (const float*)d_in[0];    // [32,256,32,32]
  const float* E = (const float*)d_in[1];    // [1024,256]
  float* out = (float*)d_out;
  float* ws = (float*)d_ws;                  // 8192 floats of partials

  ktr<<<dim3(16, 4), 256, 0, stream>>>(E, out);
  kse<<<dim3(4), 256, 0, stream>>>(out);
  kmain<<<dim3(16, 32), 256, 0, stream>>>(z, out);
  kout<<<dim3(8192), 256, 0, stream>>>(z, E, out, ws);
  kfin<<<dim3(1), 256, 0, stream>>>(ws, out);
}